// Round 6
// baseline (108.763 us; speedup 1.0000x reference)
//
#include <hip/hip_runtime.h>
#include <hip/hip_bf16.h>

#define TDEPTH 6
#define NLEAF 64
#define NGATE 63
#define INF 512
#define OUTF 512
#define BATCH 1024

#define BM 256
#define BN 64
#define THREADS 256
#define KCH 513   // 512 real i-chunks + 1 virtual bias chunk (x==1, W=pb)

typedef __attribute__((ext_vector_type(4)))  float f32x4;
typedef __attribute__((ext_vector_type(16))) float f32x16;
typedef __attribute__((ext_vector_type(8)))  __bf16 bf16x8;

// ---------------- kernel 1: leaf probabilities ----------------
__global__ __launch_bounds__(256) void leaf_kernel(
    const float* __restrict__ x, const float* __restrict__ gw,
    const float* __restrict__ gb, float* __restrict__ leaf) {
  const int wid = threadIdx.x >> 6, lane = threadIdx.x & 63;
  const int b = blockIdx.x * 4 + wid;
  __shared__ float g[4][NLEAF];
  if (lane < NGATE) {
    const float* xr = x + (size_t)b * INF;
    float a0 = 0.f, a1 = 0.f, a2 = 0.f, a3 = 0.f;
    #pragma unroll 4
    for (int i = 0; i < INF; i += 4) {
      a0 += xr[i + 0] * gw[(i + 0) * NGATE + lane];
      a1 += xr[i + 1] * gw[(i + 1) * NGATE + lane];
      a2 += xr[i + 2] * gw[(i + 2) * NGATE + lane];
      a3 += xr[i + 3] * gw[(i + 3) * NGATE + lane];
    }
    float t = (a0 + a1) + (a2 + a3) + gb[lane];
    g[wid][lane] = 1.0f / (1.0f + __expf(-t));
  }
  __syncthreads();
  float p = 1.0f;
  #pragma unroll
  for (int d = 0; d < TDEPTH; d++) {
    int prefix = lane >> (TDEPTH - 1 - d);
    int node = (1 << d) - 1 + (prefix >> 1);
    float gv = g[wid][node];
    p *= (prefix & 1) ? (1.0f - gv) : gv;
  }
  leaf[(size_t)b * NLEAF + lane] = p;
}

// async 16B global -> LDS (linear dest, wave-uniform base + lane*16)
__device__ __forceinline__ void gload_lds16(const void* g, void* l) {
  __builtin_amdgcn_global_load_lds(
      (const __attribute__((address_space(1))) void*)g,
      (__attribute__((address_space(3))) void*)l, 16, 0, 0);
}

// end-of-step sync: drain staging (vmcnt) + LDS ops, then barrier
__device__ __forceinline__ void sync_step() {
  __builtin_amdgcn_sched_barrier(0);
  asm volatile("s_waitcnt vmcnt(0) lgkmcnt(0)" ::: "memory");
  __builtin_amdgcn_s_barrier();
  __builtin_amdgcn_sched_barrier(0);
}

// ---------------- kernel 2: fused GEMM (2-phase, gload_lds) ----------------
// out_partial[s] += (x[b,i]*leaf[b,l]) * pw[o,i,l] over this block's K-slice.
// 4 waves, wave tile 64m x 64o, mfma_f32_32x32x16_bf16.
// B staged f32 via global_load_lds with source-side XOR pre-swizzle.
template <int S>
__global__ __launch_bounds__(THREADS, 3) void gemm_kernel(
    const float* __restrict__ x, const float* __restrict__ pw,
    const float* __restrict__ pb, const float* __restrict__ leaf,
    float* __restrict__ partial) {
  constexpr int XN = KCH / S;   // real steps per block (16 for S=32)
  __shared__ __align__(16) unsigned char Bsm[2][BN * 256];  // 2 x 16 KB f32
  __shared__ __align__(16) float xsm[XN * BM];              // transposed [t][row]

  const int tid = threadIdx.x, lane = tid & 63, w = tid >> 6;
  const int lo = lane & 31, half = lane >> 5;

  // XCD-chunked bijective swizzle: the 4 mb-sharers of a (nb,s) B-slice are
  // adjacent logical ids inside one XCD's contiguous chunk.
  constexpr int NWG = 4 * 8 * S;
  const int L = (blockIdx.x & 7) * (NWG / 8) + (blockIdx.x >> 3);
  const int mb = L & 3;
  const int pair = L >> 2;
  const int nb = pair & 7, s = pair >> 3;
  const int m0 = mb * BM, n0 = nb * BN;
  const int cs = XN * s;
  const bool bias = (s == S - 1);

  // staging: chunk c = w*4+j covers LDS rows 4c..4c+3; this lane handles
  // row r = w*16 + j*4 + (lane>>4), 16B granule (lane&15), XOR-pre-swizzled.
  const int lq = lane >> 4;
  const unsigned cb = (unsigned)(lane & 15) * 16;
  unsigned pwoff[4];
  #pragma unroll
  for (int j = 0; j < 4; j++) {
    int r = w * 16 + j * 4 + lq;
    pwoff[j] = (unsigned)(n0 + r) * (unsigned)(INF * NLEAF * 4) +
               (cb ^ ((unsigned)(r & 7) << 4));
  }
  const char* pwc = (const char*)pw;
  const char* pbc = (const char*)pb;

  // stage x slice transposed: xsm[t][row]; rows m0..m0+255, t in [0,XN)
  {
    const float* src = x + (size_t)(m0 + tid) * INF + cs;
    float v[XN];
    #pragma unroll
    for (int c = 0; c < XN; c += 4) {
      f32x4 t4v = *(const f32x4*)(src + c);
      v[c] = t4v[0]; v[c + 1] = t4v[1]; v[c + 2] = t4v[2]; v[c + 3] = t4v[3];
    }
    #pragma unroll
    for (int c = 0; c < XN; c++) xsm[c * BM + tid] = v[c];
  }

  // resident leaf fragments: 2 m-subtile rows x 32 f32 (this lane's k-half)
  f32x4 lf[2][4][2];
  #pragma unroll
  for (int mr = 0; mr < 2; mr++) {
    const float* lr = leaf + (size_t)(m0 + w * 64 + mr * 32 + lo) * NLEAF + half * 8;
    #pragma unroll
    for (int t4 = 0; t4 < 4; t4++) {
      lf[mr][t4][0] = *(const f32x4*)(lr + t4 * 16);
      lf[mr][t4][1] = *(const f32x4*)(lr + t4 * 16 + 4);
    }
  }

  auto stage = [&](int buf, int t) {
    const int i = cs + t;
    char* dstb = (char*)&Bsm[buf][0] + w * 4096;
    if (i < INF) {
      const char* srcb = pwc + (size_t)i * 256;
      #pragma unroll
      for (int j = 0; j < 4; j++) gload_lds16(srcb + pwoff[j], dstb + j * 1024);
    } else {  // virtual bias chunk: W = pb (same 256B-row layout as one i-plane)
      #pragma unroll
      for (int j = 0; j < 4; j++) {
        int r = w * 16 + j * 4 + lq;
        unsigned o = (unsigned)(n0 + r) * (unsigned)(NLEAF * 4) +
                     (cb ^ ((unsigned)(r & 7) << 4));
        gload_lds16(pbc + o, dstb + j * 1024);
      }
    }
  };

  f32x16 acc00 = (f32x16)(0.f), acc01 = (f32x16)(0.f);
  f32x16 acc10 = (f32x16)(0.f), acc11 = (f32x16)(0.f);

  const unsigned swz = (unsigned)(lo & 7) << 4;

  // prologue: stage step 0, drain, barrier
  stage(0, 0);
  sync_step();

  #pragma unroll 2
  for (int t = 0; t < XN; t++) {
    const int cur = t & 1;
    if (t + 1 < XN || bias) stage(cur ^ 1, t + 1);  // phase 1: issue prefetch

    const float xv0 = xsm[t * BM + w * 64 + lo];
    const float xv1 = xsm[t * BM + w * 64 + 32 + lo];
    const unsigned char* bufc = &Bsm[cur][0];

    #pragma unroll
    for (int t4 = 0; t4 < 4; t4++) {
      const unsigned kb = (unsigned)(t4 * 64 + half * 32);
      f32x4 b0a = *(const f32x4*)(bufc + lo * 256 + ((kb) ^ swz));
      f32x4 b0b = *(const f32x4*)(bufc + lo * 256 + ((kb + 16) ^ swz));
      f32x4 b1a = *(const f32x4*)(bufc + (32 + lo) * 256 + ((kb) ^ swz));
      f32x4 b1b = *(const f32x4*)(bufc + (32 + lo) * 256 + ((kb + 16) ^ swz));
      bf16x8 bf0, bf1;
      bf0[0] = (__bf16)b0a[0]; bf0[1] = (__bf16)b0a[1];
      bf0[2] = (__bf16)b0a[2]; bf0[3] = (__bf16)b0a[3];
      bf0[4] = (__bf16)b0b[0]; bf0[5] = (__bf16)b0b[1];
      bf0[6] = (__bf16)b0b[2]; bf0[7] = (__bf16)b0b[3];
      bf1[0] = (__bf16)b1a[0]; bf1[1] = (__bf16)b1a[1];
      bf1[2] = (__bf16)b1a[2]; bf1[3] = (__bf16)b1a[3];
      bf1[4] = (__bf16)b1b[0]; bf1[5] = (__bf16)b1b[1];
      bf1[6] = (__bf16)b1b[2]; bf1[7] = (__bf16)b1b[3];

      f32x4 p0a = lf[0][t4][0] * xv0, p0b = lf[0][t4][1] * xv0;
      f32x4 p1a = lf[1][t4][0] * xv1, p1b = lf[1][t4][1] * xv1;
      bf16x8 a0, a1;
      a0[0] = (__bf16)p0a[0]; a0[1] = (__bf16)p0a[1];
      a0[2] = (__bf16)p0a[2]; a0[3] = (__bf16)p0a[3];
      a0[4] = (__bf16)p0b[0]; a0[5] = (__bf16)p0b[1];
      a0[6] = (__bf16)p0b[2]; a0[7] = (__bf16)p0b[3];
      a1[0] = (__bf16)p1a[0]; a1[1] = (__bf16)p1a[1];
      a1[2] = (__bf16)p1a[2]; a1[3] = (__bf16)p1a[3];
      a1[4] = (__bf16)p1b[0]; a1[5] = (__bf16)p1b[1];
      a1[6] = (__bf16)p1b[2]; a1[7] = (__bf16)p1b[3];

      acc00 = __builtin_amdgcn_mfma_f32_32x32x16_bf16(a0, bf0, acc00, 0, 0, 0);
      acc01 = __builtin_amdgcn_mfma_f32_32x32x16_bf16(a0, bf1, acc01, 0, 0, 0);
      acc10 = __builtin_amdgcn_mfma_f32_32x32x16_bf16(a1, bf0, acc10, 0, 0, 0);
      acc11 = __builtin_amdgcn_mfma_f32_32x32x16_bf16(a1, bf1, acc11, 0, 0, 0);
    }
    sync_step();  // phase 2: drain prefetch, barrier, swap
  }

  if (bias) {  // extra step: A = leaf (x==1), W = pb (staged in buf[XN&1])
    const unsigned char* bufc = &Bsm[XN & 1][0];
    #pragma unroll
    for (int t4 = 0; t4 < 4; t4++) {
      const unsigned kb = (unsigned)(t4 * 64 + half * 32);
      f32x4 b0a = *(const f32x4*)(bufc + lo * 256 + ((kb) ^ swz));
      f32x4 b0b = *(const f32x4*)(bufc + lo * 256 + ((kb + 16) ^ swz));
      f32x4 b1a = *(const f32x4*)(bufc + (32 + lo) * 256 + ((kb) ^ swz));
      f32x4 b1b = *(const f32x4*)(bufc + (32 + lo) * 256 + ((kb + 16) ^ swz));
      bf16x8 bf0, bf1, a0, a1;
      bf0[0] = (__bf16)b0a[0]; bf0[1] = (__bf16)b0a[1];
      bf0[2] = (__bf16)b0a[2]; bf0[3] = (__bf16)b0a[3];
      bf0[4] = (__bf16)b0b[0]; bf0[5] = (__bf16)b0b[1];
      bf0[6] = (__bf16)b0b[2]; bf0[7] = (__bf16)b0b[3];
      bf1[0] = (__bf16)b1a[0]; bf1[1] = (__bf16)b1a[1];
      bf1[2] = (__bf16)b1a[2]; bf1[3] = (__bf16)b1a[3];
      bf1[4] = (__bf16)b1b[0]; bf1[5] = (__bf16)b1b[1];
      bf1[6] = (__bf16)b1b[2]; bf1[7] = (__bf16)b1b[3];
      a0[0] = (__bf16)lf[0][t4][0][0]; a0[1] = (__bf16)lf[0][t4][0][1];
      a0[2] = (__bf16)lf[0][t4][0][2]; a0[3] = (__bf16)lf[0][t4][0][3];
      a0[4] = (__bf16)lf[0][t4][1][0]; a0[5] = (__bf16)lf[0][t4][1][1];
      a0[6] = (__bf16)lf[0][t4][1][2]; a0[7] = (__bf16)lf[0][t4][1][3];
      a1[0] = (__bf16)lf[1][t4][0][0]; a1[1] = (__bf16)lf[1][t4][0][1];
      a1[2] = (__bf16)lf[1][t4][0][2]; a1[3] = (__bf16)lf[1][t4][0][3];
      a1[4] = (__bf16)lf[1][t4][1][0]; a1[5] = (__bf16)lf[1][t4][1][1];
      a1[6] = (__bf16)lf[1][t4][1][2]; a1[7] = (__bf16)lf[1][t4][1][3];
      acc00 = __builtin_amdgcn_mfma_f32_32x32x16_bf16(a0, bf0, acc00, 0, 0, 0);
      acc01 = __builtin_amdgcn_mfma_f32_32x32x16_bf16(a0, bf1, acc01, 0, 0, 0);
      acc10 = __builtin_amdgcn_mfma_f32_32x32x16_bf16(a1, bf0, acc10, 0, 0, 0);
      acc11 = __builtin_amdgcn_mfma_f32_32x32x16_bf16(a1, bf1, acc11, 0, 0, 0);
    }
  }

  // epilogue: partial[s][...] ; D row = (e&3)+8*(e>>2)+4*half, col = lo
  float* dst = partial + ((size_t)s * BATCH + m0 + w * 64) * OUTF + n0;
  #pragma unroll
  for (int e = 0; e < 16; e++) {
    int row = (e & 3) + 8 * (e >> 2) + 4 * half;
    dst[(size_t)row * OUTF + lo] = acc00[e];
    dst[(size_t)row * OUTF + 32 + lo] = acc01[e];
    dst[(size_t)(row + 32) * OUTF + lo] = acc10[e];
    dst[(size_t)(row + 32) * OUTF + 32 + lo] = acc11[e];
  }
}

// ---------------- kernel 3: split-K reduce ----------------
template <int S>
__global__ __launch_bounds__(256) void reduce_kernel(
    const float* __restrict__ partial, float* __restrict__ out) {
  size_t e = ((size_t)blockIdx.x * 256 + threadIdx.x) * 4;
  f32x4 sum = (f32x4){0.f, 0.f, 0.f, 0.f};
  #pragma unroll
  for (int s = 0; s < S; s++)
    sum += *(const f32x4*)(partial + (size_t)s * BATCH * OUTF + e);
  *(f32x4*)(out + e) = sum;
}

extern "C" void kernel_launch(void* const* d_in, const int* in_sizes, int n_in,
                              void* d_out, int out_size, void* d_ws, size_t ws_size,
                              hipStream_t stream) {
  const float* x  = (const float*)d_in[0];
  const float* gw = (const float*)d_in[1];
  const float* gb = (const float*)d_in[2];
  const float* pw = (const float*)d_in[3];
  const float* pb = (const float*)d_in[4];
  float* out = (float*)d_out;

  float* leaf    = (float*)d_ws;                       // 256 KB
  float* partial = (float*)((char*)d_ws + (1 << 20));

  leaf_kernel<<<BATCH / 4, 256, 0, stream>>>(x, gw, gb, leaf);

  const size_t need32 = (size_t)(1 << 20) + (size_t)32 * BATCH * OUTF * 4;
  if (ws_size >= need32) {
    gemm_kernel<32><<<4 * 8 * 32, THREADS, 0, stream>>>(x, pw, pb, leaf, partial);
    reduce_kernel<32><<<(BATCH * OUTF) / (256 * 4), 256, 0, stream>>>(partial, out);
  } else {
    gemm_kernel<16><<<4 * 8 * 16, THREADS, 0, stream>>>(x, pw, pb, leaf, partial);
    reduce_kernel<16><<<(BATCH * OUTF) / (256 * 4), 256, 0, stream>>>(partial, out);
  }
}

// Round 7
// 72.272 us; speedup vs baseline: 1.5049x; 1.5049x over previous
//
#include <hip/hip_runtime.h>
#include <hip/hip_bf16.h>

#define TDEPTH 6
#define NLEAF 64
#define NGATE 63
#define INF 512
#define OUTF 512
#define BATCH 1024

#define BM 256
#define BN 64
#define SPLITK 16
#define THREADS 256
#define KCH 513   // 512 real i-chunks + 1 virtual bias chunk (x==1, W=pb)
#define XN 32     // real i-planes per block (513/16)

typedef __attribute__((ext_vector_type(4)))  float f32x4;
typedef __attribute__((ext_vector_type(16))) float f32x16;
typedef __attribute__((ext_vector_type(8)))  __bf16 bf16x8;

// ---------------- kernel 1: leaf probabilities ----------------
__global__ __launch_bounds__(256) void leaf_kernel(
    const float* __restrict__ x, const float* __restrict__ gw,
    const float* __restrict__ gb, float* __restrict__ leaf) {
  const int wid = threadIdx.x >> 6, lane = threadIdx.x & 63;
  const int b = blockIdx.x * 4 + wid;
  __shared__ float g[4][NLEAF];
  if (lane < NGATE) {
    const float* xr = x + (size_t)b * INF;
    float a0 = 0.f, a1 = 0.f, a2 = 0.f, a3 = 0.f;
    #pragma unroll 4
    for (int i = 0; i < INF; i += 4) {
      a0 += xr[i + 0] * gw[(i + 0) * NGATE + lane];
      a1 += xr[i + 1] * gw[(i + 1) * NGATE + lane];
      a2 += xr[i + 2] * gw[(i + 2) * NGATE + lane];
      a3 += xr[i + 3] * gw[(i + 3) * NGATE + lane];
    }
    float t = (a0 + a1) + (a2 + a3) + gb[lane];
    g[wid][lane] = 1.0f / (1.0f + __expf(-t));
  }
  __syncthreads();
  float p = 1.0f;
  #pragma unroll
  for (int d = 0; d < TDEPTH; d++) {
    int prefix = lane >> (TDEPTH - 1 - d);
    int node = (1 << d) - 1 + (prefix >> 1);
    float gv = g[wid][node];
    p *= (prefix & 1) ? (1.0f - gv) : gv;
  }
  leaf[(size_t)b * NLEAF + lane] = p;
}

// async 16B global -> LDS (wave-uniform LDS base + lane*16)
__device__ __forceinline__ void gload_lds16(const void* g, void* l) {
  __builtin_amdgcn_global_load_lds(
      (const __attribute__((address_space(1))) void*)g,
      (__attribute__((address_space(3))) void*)l, 16, 0, 0);
}

// ---------------- kernel 2: fused GEMM, counted-vmcnt 3-buffer pipeline ----
// partial[s][b][o] = sum over K-slice of (x[b,i]*leaf[b,l]) * pw[o,i,l]
// 4 waves (4m x 1n), wave tile 64m x 64o, mfma_f32_32x32x16_bf16.
// B: f32 via global_load_lds, 3 buffers, stage t+2 at top, vmcnt(4)+barrier
// at bottom (stage t+1 guaranteed landed; t+2's 4 loads stay in flight).
__global__ __launch_bounds__(THREADS, 2) void gemm_kernel(
    const float* __restrict__ x, const float* __restrict__ pw,
    const float* __restrict__ pb, const float* __restrict__ leaf,
    float* __restrict__ partial) {
  __shared__ __align__(16) unsigned char Bsm[3][BN * 256];  // 3 x 16 KB f32
  __shared__ __align__(16) __bf16 xsm[XN * BM];             // [t][row], 16 KB

  const int tid = threadIdx.x, lane = tid & 63, w = tid >> 6;
  const int lo = lane & 31, half = lane >> 5;

  // XCD-chunked swizzle: 512 blocks -> 8 chunks of 64; the 4 mb-sharers of a
  // (nb,s) B-slice are adjacent inside one chunk (one XCD's L2).
  const int L = (blockIdx.x & 7) * 64 + (blockIdx.x >> 3);
  const int mb = L & 3;
  const int rest = L >> 2;            // 0..127 = (nb, s)
  const int nb = rest & 7, s = rest >> 3;
  const int m0 = mb * BM, n0 = nb * BN;
  const int cs = XN * s;
  const int nreal = XN;                               // 32 real planes
  const int total = XN + ((s == SPLITK - 1) ? 1 : 0); // +1 bias step on s=15

  // resident leaf fragments: 2 m-subtiles x 32 f32 (this lane's k-half)
  f32x4 lf[2][4][2];
  #pragma unroll
  for (int mr = 0; mr < 2; mr++) {
    const float* lr = leaf + (size_t)(m0 + w * 64 + mr * 32 + lo) * NLEAF + half * 8;
    #pragma unroll
    for (int t4 = 0; t4 < 4; t4++) {
      lf[mr][t4][0] = *(const f32x4*)(lr + t4 * 16);
      lf[mr][t4][1] = *(const f32x4*)(lr + t4 * 16 + 4);
    }
  }

  // stage x slice -> bf16 transposed [t][row] (writes stride-1, reads 2-way)
  {
    const float* src = x + (size_t)(m0 + tid) * INF + cs;
    #pragma unroll
    for (int c4 = 0; c4 < XN / 4; c4++) {
      f32x4 v = *(const f32x4*)(src + c4 * 4);
      #pragma unroll
      for (int j = 0; j < 4; j++)
        xsm[(c4 * 4 + j) * BM + tid] = (__bf16)v[j];
    }
  }

  // staging addresses: wave w covers LDS rows w*16..w*16+15 (4 KB chunk);
  // lane handles row r = w*16 + j*4 + (lane>>4), 16B granule (lane&15),
  // XOR-pre-swizzled on the global side (rule 21: linear LDS dest).
  const int lq = lane >> 4;
  const unsigned cb = (unsigned)(lane & 15) * 16;
  unsigned pwoff[4];
  #pragma unroll
  for (int j = 0; j < 4; j++) {
    int r = w * 16 + j * 4 + lq;
    pwoff[j] = (unsigned)(n0 + r) * (unsigned)(INF * NLEAF * 4) +
               (cb ^ ((unsigned)(r & 7) << 4));
  }
  const char* pwc = (const char*)pw;
  const char* pbc = (const char*)pb;

  auto stage = [&](char* dstb_, int t) {
    char* dstb = dstb_ + w * 4096;
    const int i = cs + t;
    if (i < INF) {
      const char* srcb = pwc + (size_t)i * 256;
      #pragma unroll
      for (int j = 0; j < 4; j++) gload_lds16(srcb + pwoff[j], dstb + j * 1024);
    } else {  // virtual bias chunk: W = pb (same 256B-per-row layout)
      #pragma unroll
      for (int j = 0; j < 4; j++) {
        int r = w * 16 + j * 4 + lq;
        unsigned o = (unsigned)(n0 + r) * (unsigned)(NLEAF * 4) +
                     (cb ^ ((unsigned)(r & 7) << 4));
        gload_lds16(pbc + o, dstb + j * 1024);
      }
    }
  };

  f32x16 acc00 = (f32x16)(0.f), acc01 = (f32x16)(0.f);
  f32x16 acc10 = (f32x16)(0.f), acc11 = (f32x16)(0.f);
  const unsigned swz = (unsigned)(lo & 7) << 4;

  auto do_step = [&](const char* bufc, int t) {
    float xv0, xv1;
    if (t < nreal) {
      xv0 = (float)xsm[t * BM + w * 64 + lo];
      xv1 = (float)xsm[t * BM + w * 64 + 32 + lo];
    } else {
      xv0 = 1.0f; xv1 = 1.0f;   // bias step: x == 1
    }
    #pragma unroll
    for (int t4 = 0; t4 < 4; t4++) {
      const unsigned kb = (unsigned)(t4 * 64 + half * 32);
      f32x4 b0a = *(const f32x4*)(bufc + lo * 256 + ((kb) ^ swz));
      f32x4 b0b = *(const f32x4*)(bufc + lo * 256 + ((kb + 16) ^ swz));
      f32x4 b1a = *(const f32x4*)(bufc + (32 + lo) * 256 + ((kb) ^ swz));
      f32x4 b1b = *(const f32x4*)(bufc + (32 + lo) * 256 + ((kb + 16) ^ swz));
      bf16x8 bf0, bf1;
      bf0[0] = (__bf16)b0a[0]; bf0[1] = (__bf16)b0a[1];
      bf0[2] = (__bf16)b0a[2]; bf0[3] = (__bf16)b0a[3];
      bf0[4] = (__bf16)b0b[0]; bf0[5] = (__bf16)b0b[1];
      bf0[6] = (__bf16)b0b[2]; bf0[7] = (__bf16)b0b[3];
      bf1[0] = (__bf16)b1a[0]; bf1[1] = (__bf16)b1a[1];
      bf1[2] = (__bf16)b1a[2]; bf1[3] = (__bf16)b1a[3];
      bf1[4] = (__bf16)b1b[0]; bf1[5] = (__bf16)b1b[1];
      bf1[6] = (__bf16)b1b[2]; bf1[7] = (__bf16)b1b[3];

      f32x4 p0a = lf[0][t4][0] * xv0, p0b = lf[0][t4][1] * xv0;
      f32x4 p1a = lf[1][t4][0] * xv1, p1b = lf[1][t4][1] * xv1;
      bf16x8 a0, a1;
      a0[0] = (__bf16)p0a[0]; a0[1] = (__bf16)p0a[1];
      a0[2] = (__bf16)p0a[2]; a0[3] = (__bf16)p0a[3];
      a0[4] = (__bf16)p0b[0]; a0[5] = (__bf16)p0b[1];
      a0[6] = (__bf16)p0b[2]; a0[7] = (__bf16)p0b[3];
      a1[0] = (__bf16)p1a[0]; a1[1] = (__bf16)p1a[1];
      a1[2] = (__bf16)p1a[2]; a1[3] = (__bf16)p1a[3];
      a1[4] = (__bf16)p1b[0]; a1[5] = (__bf16)p1b[1];
      a1[6] = (__bf16)p1b[2]; a1[7] = (__bf16)p1b[3];

      acc00 = __builtin_amdgcn_mfma_f32_32x32x16_bf16(a0, bf0, acc00, 0, 0, 0);
      acc01 = __builtin_amdgcn_mfma_f32_32x32x16_bf16(a0, bf1, acc01, 0, 0, 0);
      acc10 = __builtin_amdgcn_mfma_f32_32x32x16_bf16(a1, bf0, acc10, 0, 0, 0);
      acc11 = __builtin_amdgcn_mfma_f32_32x32x16_bf16(a1, bf1, acc11, 0, 0, 0);
    }
  };

  char* bA = (char*)&Bsm[0][0];   // compute from
  char* bB = (char*)&Bsm[1][0];   // next
  char* bC = (char*)&Bsm[2][0];   // stage into

  // prologue: stage steps 0,1; drain all but stage(1)'s 4 loads; barrier
  stage(bA, 0);
  stage(bB, 1);
  __builtin_amdgcn_sched_barrier(0);
  asm volatile("s_waitcnt vmcnt(4) lgkmcnt(0)" ::: "memory");
  __builtin_amdgcn_s_barrier();
  __builtin_amdgcn_sched_barrier(0);

  // main loop: counted vmcnt — stage(t+2) stays in flight across the barrier
  for (int t = 0; t < total - 2; ++t) {
    stage(bC, t + 2);
    do_step(bA, t);
    __builtin_amdgcn_sched_barrier(0);
    asm volatile("s_waitcnt vmcnt(4)" ::: "memory");
    __builtin_amdgcn_s_barrier();
    __builtin_amdgcn_sched_barrier(0);
    char* tmp = bA; bA = bB; bB = bC; bC = tmp;
  }
  // tail: step total-2 (wait everything), then step total-1
  do_step(bA, total - 2);
  __builtin_amdgcn_sched_barrier(0);
  asm volatile("s_waitcnt vmcnt(0)" ::: "memory");
  __builtin_amdgcn_s_barrier();
  __builtin_amdgcn_sched_barrier(0);
  do_step(bB, total - 1);

  // epilogue: partial[s]; D row = (e&3)+8*(e>>2)+4*half, col = lo
  float* dst = partial + ((size_t)s * BATCH + m0 + w * 64) * OUTF + n0;
  #pragma unroll
  for (int e = 0; e < 16; e++) {
    int row = (e & 3) + 8 * (e >> 2) + 4 * half;
    dst[(size_t)row * OUTF + lo] = acc00[e];
    dst[(size_t)row * OUTF + 32 + lo] = acc01[e];
    dst[(size_t)(row + 32) * OUTF + lo] = acc10[e];
    dst[(size_t)(row + 32) * OUTF + 32 + lo] = acc11[e];
  }
}

// ---------------- kernel 3: split-K reduce ----------------
__global__ __launch_bounds__(256) void reduce_kernel(
    const float* __restrict__ partial, float* __restrict__ out) {
  size_t e = ((size_t)blockIdx.x * 256 + threadIdx.x) * 4;
  f32x4 sum = (f32x4){0.f, 0.f, 0.f, 0.f};
  #pragma unroll
  for (int s = 0; s < SPLITK; s++)
    sum += *(const f32x4*)(partial + (size_t)s * BATCH * OUTF + e);
  *(f32x4*)(out + e) = sum;
}

extern "C" void kernel_launch(void* const* d_in, const int* in_sizes, int n_in,
                              void* d_out, int out_size, void* d_ws, size_t ws_size,
                              hipStream_t stream) {
  const float* x  = (const float*)d_in[0];
  const float* gw = (const float*)d_in[1];
  const float* gb = (const float*)d_in[2];
  const float* pw = (const float*)d_in[3];
  const float* pb = (const float*)d_in[4];
  float* out = (float*)d_out;

  float* leaf    = (float*)d_ws;                       // 256 KB
  float* partial = (float*)((char*)d_ws + (1 << 20));  // 16 x 2 MB = 32 MB

  leaf_kernel<<<BATCH / 4, 256, 0, stream>>>(x, gw, gb, leaf);
  gemm_kernel<<<4 * 8 * SPLITK, THREADS, 0, stream>>>(x, pw, pb, leaf, partial);
  reduce_kernel<<<(BATCH * OUTF) / (256 * 4), 256, 0, stream>>>(partial, out);
}